// Round 3
// baseline (2551.244 us; speedup 1.0000x reference)
//
#include <hip/hip_runtime.h>
#include <math.h>

#define NB 8
#define NN 2048
#define ND 128
#define NITER 32

// eps = blur^2 = (5e-5)^2 = 2.5e-9
#define EPS_F   2.5e-9f
#define HSCALE  (0.5f / EPS_F)
#define LNEG    (-7.624618986159399f)   /* loga = logb = -log(2048) */

// Scaled-domain math (F = f/eps etc., M_ij = dot_ij/eps, h_i = 0.5*|x_i|^2/eps):
//   f-pass:  Fa_i = LNEG - lse_j(Gt_j + M_ij)            (Fa = loga + F - hx)
//   g-pass:  Gt_j = LNEG - lse_i(Fa_i + M_ij)            (Gt = logb + G - hy)
//   sym:     P'_i = 0.5*(P_i + h_i - lse_j(Pa_j + M_ij)),  Pa = loga + P - h
// M stored quantized u8 per-row: M_ij = q_ij * S_row(i), S = |x_i|*nmax/(255*eps).
// Qyx = transpose of Mxy quantized with per-COLUMN (=its own row) scales, so the
// g-update is also a coalesced row pass.

__device__ __forceinline__ void olse_merge(float& m, float& s, float m2, float s2) {
    float mx = fmaxf(m, m2);
    s = s * __expf(m - mx) + s2 * __expf(m2 - mx);
    m = mx;
}

// ---------- preprocessing ----------

// wx[d] = sum_t x[0,t,d]^2  (reference quirk: batch 0 only), same for y
__global__ __launch_bounds__(256) void k_colsum(const float* __restrict__ x,
                                                const float* __restrict__ y,
                                                float* __restrict__ wx,
                                                float* __restrict__ wy) {
    const float* in = blockIdx.y ? y : x;
    float* w = blockIdx.y ? wy : wx;
    int d = blockIdx.x;
    int t = threadIdx.x;
    float sum = 0.f;
    for (int k = t; k < NN; k += 256) {
        float v = in[(size_t)k * ND + d];
        sum += v * v;
    }
    for (int off = 32; off > 0; off >>= 1) sum += __shfl_down(sum, off);
    __shared__ float ls[4];
    if ((t & 63) == 0) ls[t >> 6] = sum;
    __syncthreads();
    if (t == 0) w[d] = ls[0] + ls[1] + ls[2] + ls[3];
}

// X2 = x^2 / wx; h = 0.5*|X2 row|^2/eps; rn = |X2 row|
__global__ __launch_bounds__(128) void k_norm(const float* __restrict__ x,
                                              const float* __restrict__ y,
                                              const float* __restrict__ wx,
                                              const float* __restrict__ wy,
                                              float* __restrict__ X2,
                                              float* __restrict__ Y2,
                                              float* __restrict__ hx,
                                              float* __restrict__ hy,
                                              float* __restrict__ rnx,
                                              float* __restrict__ rny) {
    int gx = blockIdx.x;                 // b*NN + i
    const float* in = blockIdx.y ? y : x;
    const float* w  = blockIdx.y ? wy : wx;
    float* o  = blockIdx.y ? Y2 : X2;
    float* h  = blockIdx.y ? hy : hx;
    float* rn = blockIdx.y ? rny : rnx;
    int d = threadIdx.x;
    size_t base = (size_t)gx * ND;
    float v = in[base + d];
    float v2 = (v * v) / w[d];
    o[base + d] = v2;
    float sq = v2 * v2;
    for (int off = 32; off > 0; off >>= 1) sq += __shfl_down(sq, off);
    __shared__ float ls[2];
    if ((d & 63) == 0) ls[d >> 6] = sq;
    __syncthreads();
    if (d == 0) {
        float ss = ls[0] + ls[1];
        h[gx] = ss * HSCALE;
        rn[gx] = sqrtf(ss);
    }
}

// per-batch max row norm
__global__ __launch_bounds__(256) void k_batchmax(const float* __restrict__ rnx,
                                                  const float* __restrict__ rny,
                                                  float* __restrict__ nxmax,
                                                  float* __restrict__ nymax) {
    const float* rn = blockIdx.y ? rny : rnx;
    float* o = blockIdx.y ? nymax : nxmax;
    int b = blockIdx.x, t = threadIdx.x;
    float mx = 0.f;
    for (int i = t; i < NN; i += 256) mx = fmaxf(mx, rn[(size_t)b * NN + i]);
    for (int off = 32; off > 0; off >>= 1) mx = fmaxf(mx, __shfl_down(mx, off));
    __shared__ float ls[4];
    if ((t & 63) == 0) ls[t >> 6] = mx;
    __syncthreads();
    if (t == 0) o[b] = fmaxf(fmaxf(ls[0], ls[1]), fmaxf(ls[2], ls[3]));
}

// per-row quantization constants for the four quantized matrices
__global__ __launch_bounds__(256) void k_scales(const float* __restrict__ rnx,
                                                const float* __restrict__ rny,
                                                const float* __restrict__ nxmax,
                                                const float* __restrict__ nymax,
                                                float* __restrict__ invxy, float* __restrict__ sxy,
                                                float* __restrict__ invyx, float* __restrict__ syx,
                                                float* __restrict__ invxx, float* __restrict__ sxx,
                                                float* __restrict__ invyy, float* __restrict__ syy) {
    int i = blockIdx.x * 256 + threadIdx.x;
    int b = i >> 11;
    float nx = rnx[i], ny = rny[i];
    float bxy = nx * nymax[b];
    float byx = ny * nxmax[b];
    float bxx = nx * nxmax[b];
    float byy = ny * nymax[b];
    invxy[i] = 255.f / bxy; sxy[i] = bxy / (255.f * EPS_F);
    invyx[i] = 255.f / byx; syx[i] = byx / (255.f * EPS_F);
    invxx[i] = 255.f / bxx; sxx[i] = bxx / (255.f * EPS_F);
    invyy[i] = 255.f / byy; syy[i] = byy / (255.f * EPS_F);
}

__global__ __launch_bounds__(256) void k_init(const float* __restrict__ hx,
                                              const float* __restrict__ hy,
                                              float* __restrict__ Gt,
                                              float* __restrict__ Px, float* __restrict__ Pax,
                                              float* __restrict__ Py, float* __restrict__ Pay) {
    int tid = blockIdx.x * 256 + threadIdx.x;
    Gt[tid]  = LNEG - hy[tid];
    Px[tid]  = 0.f;
    Py[tid]  = 0.f;
    Pax[tid] = LNEG - hx[tid];
    Pay[tid] = LNEG - hy[tid];
}

__device__ __forceinline__ unsigned int pack4(const float* a, float iv) {
    int q0 = (int)fmaf(a[0], iv, 0.5f); q0 = q0 > 255 ? 255 : q0;
    int q1 = (int)fmaf(a[1], iv, 0.5f); q1 = q1 > 255 ? 255 : q1;
    int q2 = (int)fmaf(a[2], iv, 0.5f); q2 = q2 > 255 ? 255 : q2;
    int q3 = (int)fmaf(a[3], iv, 0.5f); q3 = q3 > 255 ? 255 : q3;
    return (unsigned int)q0 | ((unsigned int)q1 << 8) | ((unsigned int)q2 << 16) | ((unsigned int)q3 << 24);
}

// ---------- GEMM: acc = dot(A_i, B_j); writes row-quant u8 C, and (DO_T) col-quant transposed Ct ----------
// 128x128 tile, BK=32, 256 threads, 8x8 acc/thread. Q stores staged via LDS for
// full-cache-line coalesced writes.
template<bool DO_T>
__global__ __launch_bounds__(256) void k_gemm(const float* __restrict__ A,
                                              const float* __restrict__ B,
                                              const float* __restrict__ invA,
                                              const float* __restrict__ invB,
                                              unsigned char* __restrict__ C,
                                              unsigned char* __restrict__ Ct) {
    __shared__ float As[32][132];
    __shared__ float Bs[32][132];
    __shared__ unsigned char T[128][144];
    int bi = blockIdx.x, bj = blockIdx.y, b = blockIdx.z;
    const float* Ab = A + ((size_t)b * NN + (size_t)bi * 128) * ND;
    const float* Bb = B + ((size_t)b * NN + (size_t)bj * 128) * ND;
    int t = threadIdx.x;
    int tx = t & 15, ty = t >> 4;
    float acc[8][8];
#pragma unroll
    for (int i = 0; i < 8; ++i)
#pragma unroll
        for (int j = 0; j < 8; ++j) acc[i][j] = 0.f;
    // preload row quant scales (rows owned by this thread)
    float ivr[8];
#pragma unroll
    for (int i = 0; i < 8; ++i) {
        int m = ((i & 4) << 4) + 4 * ty + (i & 3);
        ivr[i] = invA[(size_t)b * NN + (size_t)bi * 128 + m];
    }
    int lr = t >> 3;            // 0..31
    int kq = (t & 7) << 2;      // k-quad
    for (int kt = 0; kt < ND; kt += 32) {
        __syncthreads();
#pragma unroll
        for (int s2 = 0; s2 < 4; ++s2) {
            int r = lr + (s2 << 5);
            float4 av = *(const float4*)(Ab + (size_t)r * ND + kt + kq);
            As[kq + 0][r] = av.x; As[kq + 1][r] = av.y; As[kq + 2][r] = av.z; As[kq + 3][r] = av.w;
            float4 bv = *(const float4*)(Bb + (size_t)r * ND + kt + kq);
            Bs[kq + 0][r] = bv.x; Bs[kq + 1][r] = bv.y; Bs[kq + 2][r] = bv.z; Bs[kq + 3][r] = bv.w;
        }
        __syncthreads();
#pragma unroll
        for (int k = 0; k < 32; ++k) {
            float a[8], bb[8];
            *(float4*)(a + 0)  = *(const float4*)&As[k][4 * ty];
            *(float4*)(a + 4)  = *(const float4*)&As[k][64 + 4 * ty];
            *(float4*)(bb + 0) = *(const float4*)&Bs[k][4 * tx];
            *(float4*)(bb + 4) = *(const float4*)&Bs[k][64 + 4 * tx];
#pragma unroll
            for (int i = 0; i < 8; ++i)
#pragma unroll
                for (int j = 0; j < 8; ++j)
                    acc[i][j] = fmaf(a[i], bb[j], acc[i][j]);
        }
    }
    // ---- pass 1: row-quantized tile -> LDS -> coalesced full-line stores ----
    __syncthreads();
#pragma unroll
    for (int i = 0; i < 8; ++i) {
        int m = ((i & 4) << 4) + 4 * ty + (i & 3);
        *(unsigned int*)&T[m][4 * tx]      = pack4(&acc[i][0], ivr[i]);
        *(unsigned int*)&T[m][64 + 4 * tx] = pack4(&acc[i][4], ivr[i]);
    }
    __syncthreads();
    {
        int r = t >> 1, hf = t & 1;
        size_t grow = (size_t)b * NN + (size_t)bi * 128 + r;
        unsigned char* dst = C + grow * NN + (size_t)bj * 128 + 64 * hf;
        const uint4* src = (const uint4*)&T[r][64 * hf];
        uint4 v0 = src[0], v1 = src[1], v2 = src[2], v3 = src[3];
        *(uint4*)(dst + 0)  = v0;
        *(uint4*)(dst + 16) = v1;
        *(uint4*)(dst + 32) = v2;
        *(uint4*)(dst + 48) = v3;
    }
    if (DO_T) {
        // ---- pass 2: column-quantized transposed tile ----
        float ivt[8];
#pragma unroll
        for (int j = 0; j < 8; ++j) {
            int jl = (j < 4) ? (4 * tx + j) : (64 + 4 * tx + (j - 4));
            ivt[j] = invB[(size_t)b * NN + (size_t)bj * 128 + jl];
        }
        __syncthreads();
#pragma unroll
        for (int i = 0; i < 8; ++i) {
            int m = ((i & 4) << 4) + 4 * ty + (i & 3);
#pragma unroll
            for (int j = 0; j < 8; ++j) {
                int jl = (j < 4) ? (4 * tx + j) : (64 + 4 * tx + (j - 4));
                int q = (int)fmaf(acc[i][j], ivt[j], 0.5f);
                T[jl][m] = (unsigned char)(q > 255 ? 255 : q);
            }
        }
        __syncthreads();
        {
            int r = t >> 1, hf = t & 1;
            size_t grow = (size_t)b * NN + (size_t)bj * 128 + r;   // row in transposed matrix
            unsigned char* dst = Ct + grow * NN + (size_t)bi * 128 + 64 * hf;
            const uint4* src = (const uint4*)&T[r][64 * hf];
            uint4 v0 = src[0], v1 = src[1], v2 = src[2], v3 = src[3];
            *(uint4*)(dst + 0)  = v0;
            *(uint4*)(dst + 16) = v1;
            *(uint4*)(dst + 32) = v2;
            *(uint4*)(dst + 48) = v3;
        }
    }
}

// ---------- iteration kernel: two row-lse modes per launch ----------
// mode 0: out0[gx] = LNEG - lse(v0 + Q0row*S0)        (f-pass or g-pass)
// mode 1: sym update: pn = 0.5*(P_o + h - lse(v1 + Q1row*S1)); P_n = pn; Pa_n = LNEG + pn - h
__global__ __launch_bounds__(256) void k_iter(
    const unsigned char* __restrict__ Q0, const float* __restrict__ S0,
    const float* __restrict__ v0, float* __restrict__ out0,
    const unsigned char* __restrict__ Q1, const float* __restrict__ S1,
    const float* __restrict__ v1,
    const float* __restrict__ P_o, float* __restrict__ P_n, float* __restrict__ Pa_n,
    const float* __restrict__ h) {
    int lane = threadIdx.x & 63;
    int w    = threadIdx.x >> 6;
    int gx   = blockIdx.x * 4 + w;      // group-relative b*NN + row
    int mode = blockIdx.y;
    int brel = gx >> 11;
    const unsigned char* row = (mode ? Q1 : Q0) + ((size_t)gx << 11);
    const float* v = (mode ? v1 : v0) + ((size_t)brel << 11);
    float si = (mode ? S1 : S0)[gx];

    uint4 qa = *(const uint4*)(row + lane * 32);
    uint4 qb = *(const uint4*)(row + lane * 32 + 16);
    unsigned int qs[8] = {qa.x, qa.y, qa.z, qa.w, qb.x, qb.y, qb.z, qb.w};
    const float* vv = v + lane * 32;
    float vals[32];
#pragma unroll
    for (int u = 0; u < 8; ++u) {
        float4 vf = *(const float4*)(vv + u * 4);
        unsigned int q = qs[u];
        vals[u * 4 + 0] = fmaf((float)(q & 0xffu), si, vf.x);
        vals[u * 4 + 1] = fmaf((float)((q >> 8) & 0xffu), si, vf.y);
        vals[u * 4 + 2] = fmaf((float)((q >> 16) & 0xffu), si, vf.z);
        vals[u * 4 + 3] = fmaf((float)(q >> 24), si, vf.w);
    }
    float mx = vals[0];
#pragma unroll
    for (int i = 1; i < 32; ++i) mx = fmaxf(mx, vals[i]);
#pragma unroll
    for (int off = 32; off > 0; off >>= 1) mx = fmaxf(mx, __shfl_xor(mx, off));
    float s0 = 0.f, s1 = 0.f, s2 = 0.f, s3 = 0.f;
#pragma unroll
    for (int i = 0; i < 32; i += 4) {
        s0 += __expf(vals[i + 0] - mx);
        s1 += __expf(vals[i + 1] - mx);
        s2 += __expf(vals[i + 2] - mx);
        s3 += __expf(vals[i + 3] - mx);
    }
    float s = (s0 + s1) + (s2 + s3);
#pragma unroll
    for (int off = 32; off > 0; off >>= 1) s += __shfl_xor(s, off);
    if (lane == 0) {
        float lse = mx + logf(s);
        if (mode == 0) {
            out0[gx] = LNEG - lse;
        } else {
            float pn = 0.5f * (P_o[gx] + h[gx] - lse);
            P_n[gx] = pn;
            Pa_n[gx] = LNEG + pn - h[gx];
        }
    }
}

// ---------- final reduction ----------
__global__ __launch_bounds__(256) void k_final(const float* __restrict__ Fa, const float* __restrict__ Gt,
                                               const float* __restrict__ Px, const float* __restrict__ Py,
                                               const float* __restrict__ hx, const float* __restrict__ hy,
                                               float* __restrict__ out) {
    int t = threadIdx.x;
    double acc = 0.0;
    for (int i = t; i < NB * NN; i += 256) {
        acc += (double)(Fa[i] + hx[i]) + (double)(Gt[i] + hy[i])
             - (double)Px[i] - (double)Py[i];
    }
    __shared__ double ld[256];
    ld[t] = acc;
    __syncthreads();
    for (int off = 128; off > 0; off >>= 1) {
        if (t < off) ld[t] += ld[t + off];
        __syncthreads();
    }
    if (t == 0) {
        double total = ld[0] - 2.0 * (double)LNEG * (double)(NB * NN);
        out[0] = (float)((double)EPS_F * total / (double)NN);
    }
}

extern "C" void kernel_launch(void* const* d_in, const int* in_sizes, int n_in,
                              void* d_out, int out_size, void* d_ws, size_t ws_size,
                              hipStream_t stream) {
    (void)in_sizes; (void)n_in; (void)out_size;
    const float* x = (const float*)d_in[0];
    const float* y = (const float*)d_in[1];
    float* out = (float*)d_out;

    char* ws = (char*)d_ws;
    size_t off = 0;
    auto alloc = [&](size_t bytes) -> char* {
        char* p = ws + off;
        off += (bytes + 255) & ~(size_t)255;
        return p;
    };

    float* X2 = (float*)alloc((size_t)NB * NN * ND * 4);
    float* Y2 = (float*)alloc((size_t)NB * NN * ND * 4);
    float* wx = (float*)alloc(ND * 4);
    float* wy = (float*)alloc(ND * 4);
    float* hx = (float*)alloc((size_t)NB * NN * 4);
    float* hy = (float*)alloc((size_t)NB * NN * 4);
    float* rnx = (float*)alloc((size_t)NB * NN * 4);
    float* rny = (float*)alloc((size_t)NB * NN * 4);
    float* nxmax = (float*)alloc(NB * 4);
    float* nymax = (float*)alloc(NB * 4);
    float* invxy = (float*)alloc((size_t)NB * NN * 4);
    float* sxy   = (float*)alloc((size_t)NB * NN * 4);
    float* invyx = (float*)alloc((size_t)NB * NN * 4);
    float* syx   = (float*)alloc((size_t)NB * NN * 4);
    float* invxx = (float*)alloc((size_t)NB * NN * 4);
    float* sxx   = (float*)alloc((size_t)NB * NN * 4);
    float* invyy = (float*)alloc((size_t)NB * NN * 4);
    float* syy   = (float*)alloc((size_t)NB * NN * 4);
    float* Fa = (float*)alloc((size_t)NB * NN * 4);
    float* Gt = (float*)alloc((size_t)NB * NN * 4);
    float *Pxb[2], *Paxb[2], *Pyb[2], *Payb[2];
    for (int i = 0; i < 2; ++i) {
        Pxb[i]  = (float*)alloc((size_t)NB * NN * 4);
        Paxb[i] = (float*)alloc((size_t)NB * NN * 4);
        Pyb[i]  = (float*)alloc((size_t)NB * NN * 4);
        Payb[i] = (float*)alloc((size_t)NB * NN * 4);
    }

    // Batch-group size: shrink if workspace is small (matrices rebuilt per group)
    size_t small_end = off;
    size_t matBytes = (size_t)NN * NN;               // 4 MB (u8)
    int G = NB;
    while (G > 1 && small_end + 4 * matBytes * (size_t)G + 4096 > ws_size) G >>= 1;
    unsigned char* Qxy = (unsigned char*)alloc(matBytes * (size_t)G);
    unsigned char* Qyx = (unsigned char*)alloc(matBytes * (size_t)G);
    unsigned char* Qxx = (unsigned char*)alloc(matBytes * (size_t)G);
    unsigned char* Qyy = (unsigned char*)alloc(matBytes * (size_t)G);

    k_colsum<<<dim3(ND, 2), 256, 0, stream>>>(x, y, wx, wy);
    k_norm<<<dim3(NB * NN, 2), 128, 0, stream>>>(x, y, wx, wy, X2, Y2, hx, hy, rnx, rny);
    k_batchmax<<<dim3(NB, 2), 256, 0, stream>>>(rnx, rny, nxmax, nymax);
    k_scales<<<dim3(NB * NN / 256), 256, 0, stream>>>(rnx, rny, nxmax, nymax,
                                                      invxy, sxy, invyx, syx,
                                                      invxx, sxx, invyy, syy);
    k_init<<<dim3(NB * NN / 256), 256, 0, stream>>>(hx, hy, Gt, Pxb[0], Paxb[0], Pyb[0], Payb[0]);

    for (int b0 = 0; b0 < NB; b0 += G) {
        size_t po = (size_t)b0 * NN;
        const float* X2g = X2 + po * ND;
        const float* Y2g = Y2 + po * ND;
        k_gemm<true><<<dim3(16, 16, G), 256, 0, stream>>>(X2g, Y2g, invxy + po, invyx + po, Qxy, Qyx);
        k_gemm<false><<<dim3(16, 16, G), 256, 0, stream>>>(X2g, X2g, invxx + po, nullptr, Qxx, nullptr);
        k_gemm<false><<<dim3(16, 16, G), 256, 0, stream>>>(Y2g, Y2g, invyy + po, nullptr, Qyy, nullptr);
        int cur = 0;
        for (int it = 0; it < NITER; ++it) {
            // phase A: f-pass (Qxy rows, old Gt) + symx update (Qxx)
            k_iter<<<dim3(G * NN / 4, 2), 256, 0, stream>>>(
                Qxy, sxy + po, Gt + po, Fa + po,
                Qxx, sxx + po, Paxb[cur] + po,
                Pxb[cur] + po, Pxb[1 - cur] + po, Paxb[1 - cur] + po, hx + po);
            // phase B: g-pass (Qyx rows, new Fa) + symy update (Qyy)
            k_iter<<<dim3(G * NN / 4, 2), 256, 0, stream>>>(
                Qyx, syx + po, Fa + po, Gt + po,
                Qyy, syy + po, Payb[cur] + po,
                Pyb[cur] + po, Pyb[1 - cur] + po, Payb[1 - cur] + po, hy + po);
            cur ^= 1;
        }
    }
    // NITER even -> final sym potentials are in buffer 0
    k_final<<<dim3(1), 256, 0, stream>>>(Fa, Gt, Pxb[0], Pyb[0], hx, hy, out);
}